// Round 22
// baseline (62.979 us; speedup 1.0000x reference)
//
#include <hip/hip_runtime.h>

#define N_ROWS 8192
#define BM 128                   // square tile edge (rows = cols per block)
#define NPANEL (N_ROWS / BM)     // 64 panels
#define NPART NPANEL             // 64 partial slots per row
#define KEXP 20.60992915f        // log2(e)/TAU

typedef __attribute__((ext_vector_type(4))) float f32x4;
typedef __attribute__((ext_vector_type(2))) long long2v;

__device__ __forceinline__ float fast_exp2(float x) {
  float r;
  asm("v_exp_f32 %0, %1" : "=v"(r) : "v"(x));
  return r;
}

// Kernel 1 (R14, unchanged): L2-normalize rows; write fp8 e4m3 in
// MFMA-FRAGMENT-PAIR order. byte = G*2048 + p*1024 + ksub*256 + (row&15)*16
// + h*8 + kk. fnA scaled by log2(e)/tau, fnB unscaled.
__global__ __launch_bounds__(256) void knorm(const float* __restrict__ feat,
                                             unsigned short* __restrict__ fnA,
                                             unsigned short* __restrict__ fnB) {
  const int wid = threadIdx.x >> 6;
  const int lane = threadIdx.x & 63;
  const int row = blockIdx.x * 4 + wid;
  const float2 v = *(const float2*)(feat + (size_t)row * 128 + lane * 2);
  float s = v.x * v.x + v.y * v.y;
#pragma unroll
  for (int m = 1; m < 64; m <<= 1) s += __shfl_xor(s, m);
  const float inv = 1.0f / fmaxf(sqrtf(s), 1e-12f);
  const float x = v.x * inv, y = v.y * inv;
  const int k = lane * 2;
  const int p = k >> 6, h = (k >> 5) & 1, ksub = (k >> 3) & 3, kk = k & 7;
  const int byteoff = ((row >> 4) << 11) + (p << 10) + (ksub << 8) +
                      ((row & 15) << 4) + (h << 3) + kk;
  const unsigned int pkB = __builtin_amdgcn_cvt_pk_fp8_f32(x, y, 0, 0);
  const unsigned int pkA = __builtin_amdgcn_cvt_pk_fp8_f32(x * KEXP, y * KEXP, 0, 0);
  fnB[byteoff >> 1] = (unsigned short)pkB;
  fnA[byteoff >> 1] = (unsigned short)pkA;
}

// Kernel 2: SYMMETRY-HALVED sim. Grid 64x64 panels; only upper triangle
// (J >= I) computes. Each off-diagonal 128x128 tile contributes its row-sums
// (over cols, slot [J][rows of I]) AND col-sums (over rows, slot [I][cols as
// rows of J]) — e(sim) and the pos mask are symmetric. Diagonal blocks write
// row-sums only. Every partial slot has exactly ONE writer -> deterministic.
// Inner tile structure = R14 (no-LDS fp8 frag-pair loads, 2 sub-tiles of 64).
__global__ __launch_bounds__(256, 4) void ksim(const unsigned short* __restrict__ fnA,
                                               const unsigned short* __restrict__ fnB,
                                               const float* __restrict__ alphap,
                                               float* __restrict__ posP,
                                               float* __restrict__ totP) {
  const int I = blockIdx.x;  // row panel
  const int J = blockIdx.y;  // col panel
  if (J < I) return;         // lower triangle: covered by (J,I) via symmetry
  __shared__ float colbuf[4][2][128];  // per-wave col partials [wave][pos/tot][col]
  const int tid = threadIdx.x;
  const int lane = tid & 63;
  const int wid = tid >> 6;
  const int r0 = I * BM;
  const int c0 = J * BM;
  const float alphaK = alphap[0] * KEXP;

  const char* __restrict__ FA = (const char*)fnA;
  const char* __restrict__ FB = (const char*)fnB;

  // A fragments: 2 m-frags x 4 ks (8B each), loaded as 2x2 16B pair-loads.
  long aR[2][4];
  {
    const int G0 = (r0 + wid * 32) >> 4;
#pragma unroll
    for (int m = 0; m < 2; m++)
#pragma unroll
      for (int p = 0; p < 2; p++) {
        const long2v t = *(const long2v*)(FA + (size_t)(G0 + m) * 2048 + p * 1024 + lane * 16);
        aR[m][2 * p] = t[0];
        aR[m][2 * p + 1] = t[1];
      }
  }

  float pp[2][4] = {{0.f}}, tp[2][4] = {{0.f}};

#pragma unroll 1
  for (int it = 0; it < 2; ++it) {  // two 64-col sub-tiles
    const char* Bb = FB + (size_t)((c0 >> 4) + it * 4) * 2048 + lane * 16;

    f32x4 acc[2][4];
#pragma unroll
    for (int m = 0; m < 2; m++)
#pragma unroll
      for (int n = 0; n < 4; n++) acc[m][n] = (f32x4){0.f, 0.f, 0.f, 0.f};

#pragma unroll
    for (int p = 0; p < 2; p++) {
      const long2v b0 = *(const long2v*)(Bb + 0 * 2048 + p * 1024);
      const long2v b1 = *(const long2v*)(Bb + 1 * 2048 + p * 1024);
      const long2v b2 = *(const long2v*)(Bb + 2 * 2048 + p * 1024);
      const long2v b3 = *(const long2v*)(Bb + 3 * 2048 + p * 1024);
#pragma unroll
      for (int m = 0; m < 2; m++) {
        acc[m][0] = __builtin_amdgcn_mfma_f32_16x16x32_fp8_fp8(aR[m][2 * p], b0[0], acc[m][0], 0, 0, 0);
        acc[m][1] = __builtin_amdgcn_mfma_f32_16x16x32_fp8_fp8(aR[m][2 * p], b1[0], acc[m][1], 0, 0, 0);
        acc[m][2] = __builtin_amdgcn_mfma_f32_16x16x32_fp8_fp8(aR[m][2 * p], b2[0], acc[m][2], 0, 0, 0);
        acc[m][3] = __builtin_amdgcn_mfma_f32_16x16x32_fp8_fp8(aR[m][2 * p], b3[0], acc[m][3], 0, 0, 0);
        acc[m][0] = __builtin_amdgcn_mfma_f32_16x16x32_fp8_fp8(aR[m][2 * p + 1], b0[1], acc[m][0], 0, 0, 0);
        acc[m][1] = __builtin_amdgcn_mfma_f32_16x16x32_fp8_fp8(aR[m][2 * p + 1], b1[1], acc[m][1], 0, 0, 0);
        acc[m][2] = __builtin_amdgcn_mfma_f32_16x16x32_fp8_fp8(aR[m][2 * p + 1], b2[1], acc[m][2], 0, 0, 0);
        acc[m][3] = __builtin_amdgcn_mfma_f32_16x16x32_fp8_fp8(aR[m][2 * p + 1], b3[1], acc[m][3], 0, 0, 0);
      }
    }

    // Epilogue: e = 2^a (A pre-scaled); row sums into pp/tp, col sums into cpp/ctp.
    float cpp[4] = {0.f, 0.f, 0.f, 0.f}, ctp[4] = {0.f, 0.f, 0.f, 0.f};
    const int cb = c0 + it * 64;
#pragma unroll
    for (int m = 0; m < 2; m++) {
      const int grb = r0 + wid * 32 + m * 16;
#pragma unroll
      for (int n = 0; n < 4; n++) {
        const int gcb = cb + n * 16;
        const f32x4 a = acc[m][n];
        if (grb == gcb) {  // diagonal fragment (only in I==J blocks)
          const int gr0 = (lane >> 4) << 2;
          const int gcl = lane & 15;
#pragma unroll
          for (int r = 0; r < 4; r++) {
            const float e = fast_exp2(a[r]);
            const float ev = (gr0 + r == gcl) ? 0.0f : e;
            const float pev = (a[r] >= alphaK) ? ev : 0.0f;
            tp[m][r] += ev;
            pp[m][r] += pev;
            ctp[n] += ev;
            cpp[n] += pev;
          }
        } else {
#pragma unroll
          for (int r = 0; r < 4; r++) {
            const float e = fast_exp2(a[r]);
            const float pev = (a[r] >= alphaK) ? e : 0.0f;
            tp[m][r] += e;
            pp[m][r] += pev;
            ctp[n] += e;
            cpp[n] += pev;
          }
        }
      }
    }

    // Fold col partials over the 4 row-groups; park this wave's slice in LDS.
#pragma unroll
    for (int n = 0; n < 4; n++) {
      float cp = cpp[n], ct = ctp[n];
      cp += __shfl_xor(cp, 16);
      cp += __shfl_xor(cp, 32);
      ct += __shfl_xor(ct, 16);
      ct += __shfl_xor(ct, 32);
      if (lane < 16) {
        colbuf[wid][0][it * 64 + n * 16 + lane] = cp;
        colbuf[wid][1][it * 64 + n * 16 + lane] = ct;
      }
    }
  }

  // Row-side: reduce across the 16 col-lanes; store slot [J][rows of I].
#pragma unroll
  for (int m = 0; m < 2; m++)
#pragma unroll
    for (int r = 0; r < 4; r++) {
      float p = pp[m][r], t = tp[m][r];
#pragma unroll
      for (int msk = 1; msk < 16; msk <<= 1) {
        p += __shfl_xor(p, msk);
        t += __shfl_xor(t, msk);
      }
      if ((lane & 15) == 0) {
        const int row = r0 + wid * 32 + m * 16 + ((lane >> 4) << 2) + r;
        posP[(size_t)J * N_ROWS + row] = p;
        totP[(size_t)J * N_ROWS + row] = t;
      }
    }

  // Col-side: combine the 4 waves' slices; store slot [I][cols of J].
  __syncthreads();
  if (I != J && tid < 128) {
    const int colg = c0 + tid;
    const float cp = colbuf[0][0][tid] + colbuf[1][0][tid] +
                     colbuf[2][0][tid] + colbuf[3][0][tid];
    const float ct = colbuf[0][1][tid] + colbuf[1][1][tid] +
                     colbuf[2][1][tid] + colbuf[3][1][tid];
    posP[(size_t)I * N_ROWS + colg] = cp;
    totP[(size_t)I * N_ROWS + colg] = ct;
  }
}

// Kernel 3a: per-row loss term over 64 partial slots, 128-row blocks -> 64 sums.
__global__ __launch_bounds__(128) void kred1(const float* __restrict__ posP,
                                             const float* __restrict__ totP,
                                             float* __restrict__ bp) {
  const int t = threadIdx.x;
  const int row = blockIdx.x * 128 + t;
  float pos = 0.f, tot = 0.f;
#pragma unroll
  for (int c = 0; c < NPART; c++) {
    pos += posP[(size_t)c * N_ROWS + row];
    tot += totP[(size_t)c * N_ROWS + row];
  }
  float term = __logf(tot + 2e-10f) - __logf(pos + 1e-10f);
#pragma unroll
  for (int m = 1; m < 64; m <<= 1) term += __shfl_xor(term, m);
  __shared__ float s2[2];
  if ((t & 63) == 0) s2[t >> 6] = term;
  __syncthreads();
  if (t == 0) bp[blockIdx.x] = s2[0] + s2[1];
}

// Kernel 3b: final mean.
__global__ void kred2(const float* __restrict__ bp, float* __restrict__ out) {
  const int l = threadIdx.x;
  float v = bp[l];
#pragma unroll
  for (int m = 1; m < 64; m <<= 1) v += __shfl_xor(v, m);
  if (l == 0) out[0] = v * (1.0f / 8192.0f);
}

extern "C" void kernel_launch(void* const* d_in, const int* in_sizes, int n_in,
                              void* d_out, int out_size, void* d_ws, size_t ws_size,
                              hipStream_t stream) {
  const float* feat = (const float*)d_in[0];
  const float* alphap = (const float*)d_in[1];
  char* ws = (char*)d_ws;
  unsigned short* fnA = (unsigned short*)ws;                // 1 MB fp8 frag-paired, x log2e/tau
  unsigned short* fnB = (unsigned short*)(ws + (1u << 20)); // 1 MB fp8 frag-paired
  float* posP = (float*)(ws + (2u << 20));                  // 2 MB (64 x 8192)
  float* totP = (float*)(ws + (4u << 20));                  // 2 MB
  float* bp = (float*)(ws + (6u << 20));                    // 256 B
  float* out = (float*)d_out;

  knorm<<<dim3(N_ROWS / 4), dim3(256), 0, stream>>>(feat, fnA, fnB);
  ksim<<<dim3(NPANEL, NPANEL), dim3(256), 0, stream>>>(fnA, fnB, alphap, posP, totP);
  kred1<<<dim3(N_ROWS / 128), dim3(128), 0, stream>>>(posP, totP, bp);
  kred2<<<dim3(1), dim3(64), 0, stream>>>(bp, out);
}